// Round 10
// baseline (115.168 us; speedup 1.0000x reference)
//
#include <hip/hip_runtime.h>
#include <stdint.h>

#define Bb 8
#define Ll 2048
#define Ss 2048
#define Dd 128
#define NSB 4
#define SCHUNK 512
#define NROWS 16384  // Bb*Ll == Bb*Ss
#define SCALE_LOG2E 92.33248261689366f  // 64 * log2(e); also the fixed softmax max

typedef __attribute__((ext_vector_type(8))) short bf16x8;
typedef __attribute__((ext_vector_type(16))) float f32x16;

__device__ __forceinline__ unsigned f2bf_pack(float a, float b) {
  unsigned ua = __float_as_uint(a); ua += 0x7fffu + ((ua >> 16) & 1u);
  unsigned ub = __float_as_uint(b); ub += 0x7fffu + ((ub >> 16) & 1u);
  return (ua >> 16) | (ub & 0xffff0000u);
}

__device__ __forceinline__ unsigned pkbf(float a, float b) {
#if __has_builtin(__builtin_amdgcn_cvt_pk_bf16_f32)
  auto r = __builtin_amdgcn_cvt_pk_bf16_f32(a, b);
  return __builtin_bit_cast(unsigned, r);
#else
  return f2bf_pack(a, b);
#endif
}

__device__ __forceinline__ void gl_lds16(const void* g, void* l) {
  __builtin_amdgcn_global_load_lds(
      (const __attribute__((address_space(1))) unsigned*)g,
      (__attribute__((address_space(3))) unsigned*)l, 16, 0, 0);
}

// Fragment-major layouts, per 32-s block = 8 slots * 1 KB = 8 KB (4096 ushort):
//  Kf slot kt, lane l=(h*32+s): K[s][d=kt*16+h*8+j]
//  Vf slot (dblk*2+t2), lane l=(h*32+dloc): V^T[d=dblk*32+dloc][s_perm]
//    s_perm = t2*16 + 4*h + (j&3) + 8*(j>>2) == S-MFMA C-reg order, so the
//    P B-fragment is exactly the packed acc registers (lane-local identity).

// ---------------- pre-pass (identical to R7, verified) ----------------
extern "C" __global__ __launch_bounds__(256)
void prep_kern(const float* __restrict__ Q, const float* __restrict__ K,
               const float* __restrict__ V,
               unsigned short* __restrict__ Qn, unsigned short* __restrict__ Kf,
               unsigned short* __restrict__ Vf) {
  __shared__ float Tf[32 * 130];
  __shared__ float Ps[32 * 8];
  __shared__ float Nr[32];
  __shared__ unsigned short Tb[32 * 128];
  const int t = threadIdx.x;
  const int bid = blockIdx.x;
  if (bid < 4096) {  // Q: one row per wave, row-major bf16 out
    const int lane = t & 63;
    const int r = bid * 4 + (t >> 6);
    float2 f = *(const float2*)(Q + (size_t)r * Dd + lane * 2);
    float ss = f.x * f.x + f.y * f.y;
#pragma unroll
    for (int m = 1; m < 64; m <<= 1) ss += __shfl_xor(ss, m, 64);
    float inv = 1.0f / fmaxf(sqrtf(ss), 1e-12f);
    *(unsigned*)(Qn + (size_t)r * Dd + lane * 2) = pkbf(f.x * inv, f.y * inv);
  } else if (bid < 4608) {  // K: 32-row block -> normalize -> frag-major
    const int kb = bid - 4096;
    const int b = kb & 7, sw = kb >> 3;
    const int sl = t >> 3, d0 = (t & 7) * 16;
    const float* src = K + ((size_t)(b * Ss + sw * 32 + sl)) * Dd + d0;
    float ss = 0.f;
#pragma unroll
    for (int i = 0; i < 4; ++i) {
      float4 v = *(const float4*)(src + i * 4);
      Tf[sl * 130 + d0 + i * 4 + 0] = v.x;
      Tf[sl * 130 + d0 + i * 4 + 1] = v.y;
      Tf[sl * 130 + d0 + i * 4 + 2] = v.z;
      Tf[sl * 130 + d0 + i * 4 + 3] = v.w;
      ss += v.x * v.x + v.y * v.y + v.z * v.z + v.w * v.w;
    }
    Ps[sl * 8 + (t & 7)] = ss;
    __syncthreads();
    if (t < 32) {
      float s = 0.f;
#pragma unroll
      for (int j = 0; j < 8; ++j) s += Ps[t * 8 + j];
      Nr[t] = 1.0f / fmaxf(sqrtf(s), 1e-12f);
    }
    __syncthreads();
    unsigned short* Ko = Kf + ((size_t)(b * 64 + sw)) * 4096;
#pragma unroll
    for (int p = 0; p < 2; ++p) {
      const int run = p * 256 + t;
      const int lane = run & 63, s = lane & 31, h = lane >> 5;
      const int d = (run >> 6) * 16 + h * 8;
      const float n = Nr[s];
      const float* row = &Tf[s * 130 + d];
      uint4 w;
      w.x = pkbf(row[0] * n, row[1] * n);
      w.y = pkbf(row[2] * n, row[3] * n);
      w.z = pkbf(row[4] * n, row[5] * n);
      w.w = pkbf(row[6] * n, row[7] * n);
      *(uint4*)(Ko + run * 8) = w;
    }
  } else {  // V: 32-row block -> transpose -> j-permuted frag-major
    const int vb = bid - 4608;
    const int b = vb & 7, sw = vb >> 3;
    const int sl = t >> 3, d0 = (t & 7) * 16;
    const float* src = V + ((size_t)(b * Ss + sw * 32 + sl)) * Dd + d0;
#pragma unroll
    for (int i = 0; i < 4; ++i) {
      float4 v = *(const float4*)(src + i * 4);
      *(unsigned*)&Tb[sl * 128 + d0 + i * 4]     = pkbf(v.x, v.y);
      *(unsigned*)&Tb[sl * 128 + d0 + i * 4 + 2] = pkbf(v.z, v.w);
    }
    __syncthreads();
    unsigned short* Vo = Vf + ((size_t)(b * 64 + sw)) * 4096;
#pragma unroll
    for (int p = 0; p < 2; ++p) {
      const int run = p * 256 + t;
      const int vslot = run >> 6, lane = run & 63;
      const int dloc = lane & 31, h = lane >> 5;
      const int dblk = vslot >> 1, t2 = vslot & 1;
      const int d = dblk * 32 + dloc;
      unsigned short w[8];
#pragma unroll
      for (int j = 0; j < 8; ++j) {
        const int sloc = t2 * 16 + 4 * h + (j & 3) + 8 * (j >> 2);
        w[j] = Tb[sloc * 128 + d];
      }
      *(uint4*)(Vo + run * 8) = *(uint4*)w;
    }
  }
}

// ---------------- main fused attention: producer/consumer wave pairs -------
// grid 1024: gid = qt*32 + b*4 + sb; WG = 4 waves, 64 q-rows.
// Waves 0,1 (A) = producers: S = K.Q^T, exp, pack P -> LDS (regs ~85).
// Waves 2,3 (B) = consumers: O += V^T.P^T from LDS P (regs ~95).
// Both roles fit <=128 regs -> 4 waves/SIMD (16 waves/CU; LDS 40 KB -> 4 WG/CU).
// 1-iter pipeline: A computes S(t+1) while B computes O(t).
extern "C" __global__ __launch_bounds__(256, 4)
void attn_kern(const unsigned short* __restrict__ Qn,
               const unsigned short* __restrict__ Kf,
               const unsigned short* __restrict__ Vf,
               unsigned short* __restrict__ Op,
               float* __restrict__ Lp) {
  __shared__ unsigned short Kl[2][8 * 512];   // 16 KB K dbuf
  __shared__ unsigned short Vl[2][8 * 512];   // 16 KB V dbuf
  __shared__ unsigned short Pl[2][2][1024];   // 8 KB P dbuf [buf][qgroup]
  const int tid = threadIdx.x, wv = tid >> 6, lane = tid & 63;
  const int lm = lane & 31, h = lane >> 5;
  const int gid = blockIdx.x;
  const int qt = gid >> 5, b = (gid >> 2) & 7, sb = gid & 3;
  const int sblk0 = sb * 16;
  const bool isA = wv < 2;
  const int g = wv & 1;                        // q-group within WG
  const int qrow = qt * 64 + g * 32 + lm;

  const unsigned short* Kc = Kf + ((size_t)(b * 64 + sblk0)) * 4096;
  const unsigned short* Vc = Vf + ((size_t)(b * 64 + sblk0)) * 4096;

  bf16x8 qf[8];
  f32x16 o[4];
  if (isA) {
    const unsigned short* Qrow = Qn + ((size_t)(b * Ll + qrow)) * Dd;
#pragma unroll
    for (int kt = 0; kt < 8; ++kt)
      qf[kt] = *(const bf16x8*)(Qrow + kt * 16 + h * 8);
  } else {
#pragma unroll
    for (int i = 0; i < 4; ++i)
#pragma unroll
      for (int r = 0; r < 16; ++r) o[i][r] = 0.f;
  }
  float lrun = 0.f;

  auto stageK = [&](int t) {  // A-wave g stages K slots g*4..g*4+3
    const unsigned short* kb = Kc + (size_t)t * 4096;
#pragma unroll
    for (int i = 0; i < 4; ++i) {
      const int sl = g * 4 + i;
      gl_lds16(kb + sl * 512 + lane * 8, &Kl[t & 1][sl * 512]);
    }
  };
  auto stageV = [&](int t) {  // B-wave g stages V slots g*4..g*4+3
    const unsigned short* vb = Vc + (size_t)t * 4096;
#pragma unroll
    for (int i = 0; i < 4; ++i) {
      const int sl = g * 4 + i;
      gl_lds16(vb + sl * 512 + lane * 8, &Vl[t & 1][sl * 512]);
    }
  };

  auto computeS = [&](int t) {  // A: S^T(t) -> exp -> P(t) into Pl[t&1][g]
    const int buf = t & 1;
    f32x16 acc;
#pragma unroll
    for (int r = 0; r < 16; ++r) acc[r] = 0.f;
#pragma unroll
    for (int kt = 0; kt < 8; ++kt) {
      bf16x8 kf = *(const bf16x8*)&Kl[buf][kt * 512 + lane * 8];
      acc = __builtin_amdgcn_mfma_f32_32x32x16_bf16(kf, qf[kt], acc, 0, 0, 0);
    }
#pragma unroll
    for (int t2 = 0; t2 < 2; ++t2) {
      float p[8];
#pragma unroll
      for (int j = 0; j < 8; ++j)
        p[j] = __builtin_amdgcn_exp2f(
            __builtin_fmaf(acc[t2 * 8 + j], SCALE_LOG2E, -SCALE_LOG2E));
      lrun += ((p[0] + p[1]) + (p[2] + p[3])) + ((p[4] + p[5]) + (p[6] + p[7]));
      uint4 fr;
      fr.x = pkbf(p[0], p[1]);
      fr.y = pkbf(p[2], p[3]);
      fr.z = pkbf(p[4], p[5]);
      fr.w = pkbf(p[6], p[7]);
      *(uint4*)&Pl[buf][g][(t2 * 64 + lane) * 8] = fr;  // ds_write_b128
    }
  };
  auto computeO = [&](int t) {  // B: O += V^T(t) . P^T(t)
    const int buf = t & 1;
#pragma unroll
    for (int t2 = 0; t2 < 2; ++t2) {
      bf16x8 pf = *(const bf16x8*)&Pl[buf][g][(t2 * 64 + lane) * 8];
#pragma unroll
      for (int dblk = 0; dblk < 4; ++dblk) {
        bf16x8 vf = *(const bf16x8*)&Vl[buf][(dblk * 2 + t2) * 512 + lane * 8];
        o[dblk] = __builtin_amdgcn_mfma_f32_32x32x16_bf16(vf, pf, o[dblk], 0, 0, 0);
      }
    }
  };

  // prologue: A stages K(0),K(1); B stages V(0). Then A computes S(0).
  if (isA) { stageK(0); stageK(1); } else { stageV(0); }
  asm volatile("s_waitcnt vmcnt(0)\n\ts_barrier" ::: "memory");
  if (isA) computeS(0);

#pragma unroll 1
  for (int t = 0; t < 16; ++t) {
    // gate: drain period-old loads + P-writes, converge.
    asm volatile("s_waitcnt vmcnt(0) lgkmcnt(0)\n\ts_barrier" ::: "memory");
    if (isA) {
      if (t + 2 < 16) stageK(t + 2);   // -> Kl[t&1] (A read it in iter t-1)
      if (t + 1 < 16) computeS(t + 1); // reads Kl[(t+1)&1], writes Pl[(t+1)&1]
    } else {
      if (t + 1 < 16) stageV(t + 1);   // -> Vl[(t+1)&1] (disjoint from reads)
      computeO(t);                      // reads Vl[t&1], Pl[t&1]
    }
  }

  if (isA) {  // epilogue A: per-row softmax denominators (shared fixed max)
    const float lt = lrun + __shfl_xor(lrun, 32, 64);
    if (h == 0) Lp[sb * NROWS + b * Ll + qrow] = lt;
  } else {    // epilogue B: partial (unnormalized) O in bf16
    unsigned short* Ob = Op + ((size_t)sb * NROWS + b * Ll + qrow) * Dd;
#pragma unroll
    for (int dblk = 0; dblk < 4; ++dblk)
#pragma unroll
      for (int gg = 0; gg < 4; ++gg) {
        uint2 w;
        w.x = pkbf(o[dblk][gg * 4 + 0], o[dblk][gg * 4 + 1]);
        w.y = pkbf(o[dblk][gg * 4 + 2], o[dblk][gg * 4 + 3]);
        *(uint2*)(Ob + dblk * 32 + gg * 8 + h * 4) = w;  // d = 32*dblk+8*gg+4*h
      }
  }
}

// ---------------- combine the NSB S-chunk partials (pure sum: shared max) ---
extern "C" __global__ __launch_bounds__(256)
void comb_kern(const unsigned short* __restrict__ Op,
               const float* __restrict__ Lp, float* __restrict__ Out) {
  const int idx = blockIdx.x * 256 + threadIdx.x;  // one thread per 4 d
  const int row = idx >> 5;
  const int dof = (idx & 31) * 4;
  float den = 0.f;
#pragma unroll
  for (int s = 0; s < NSB; ++s) den += Lp[s * NROWS + row];
  float a0 = 0.f, a1 = 0.f, a2 = 0.f, a3 = 0.f;
#pragma unroll
  for (int s = 0; s < NSB; ++s) {
    uint2 v = *(const uint2*)(Op + ((size_t)s * NROWS + row) * Dd + dof);
    a0 += __uint_as_float(v.x << 16);
    a1 += __uint_as_float(v.x & 0xffff0000u);
    a2 += __uint_as_float(v.y << 16);
    a3 += __uint_as_float(v.y & 0xffff0000u);
  }
  const float inv = 1.f / den;
  float4 r; r.x = a0 * inv; r.y = a1 * inv; r.z = a2 * inv; r.w = a3 * inv;
  *(float4*)(Out + (size_t)row * Dd + dof) = r;
}

extern "C" void kernel_launch(void* const* d_in, const int* in_sizes, int n_in,
                              void* d_out, int out_size, void* d_ws, size_t ws_size,
                              hipStream_t stream) {
  const float* Q = (const float*)d_in[0];
  const float* K = (const float*)d_in[1];
  const float* V = (const float*)d_in[2];
  float* Out = (float*)d_out;
  unsigned short* Qn = (unsigned short*)d_ws;                  // 4 MiB
  unsigned short* Kf = Qn + (size_t)NROWS * Dd;                // 4 MiB (frag-major)
  unsigned short* Vf = Kf + (size_t)NROWS * Dd;                // 4 MiB (frag-major, j-permuted)
  unsigned short* Op = Vf + (size_t)Bb * Dd * Ss;              // 16 MiB (bf16 partials)
  float* Lp = (float*)(Op + (size_t)NSB * NROWS * Dd);         // 256 KiB
  hipLaunchKernelGGL(prep_kern, dim3(4096 + 512 + 512), dim3(256), 0, stream,
                     Q, K, V, Qn, Kf, Vf);
  hipLaunchKernelGGL(attn_kern, dim3(1024), dim3(256), 0, stream, Qn, Kf, Vf, Op, Lp);
  hipLaunchKernelGGL(comb_kern, dim3(2048), dim3(256), 0, stream, Op, Lp, Out);
}

// Round 11
// 110.541 us; speedup vs baseline: 1.0419x; 1.0419x over previous
//
#include <hip/hip_runtime.h>
#include <stdint.h>

#define Bb 8
#define Ll 2048
#define Ss 2048
#define Dd 128
#define NSB 4
#define SCHUNK 512
#define NROWS 16384  // Bb*Ll == Bb*Ss
#define SCALE_LOG2E 92.33248261689366f  // 64 * log2(e); also the fixed softmax max

typedef __attribute__((ext_vector_type(8))) short bf16x8;
typedef __attribute__((ext_vector_type(16))) float f32x16;

__device__ __forceinline__ unsigned f2bf_pack(float a, float b) {
  unsigned ua = __float_as_uint(a); ua += 0x7fffu + ((ua >> 16) & 1u);
  unsigned ub = __float_as_uint(b); ub += 0x7fffu + ((ub >> 16) & 1u);
  return (ua >> 16) | (ub & 0xffff0000u);
}

__device__ __forceinline__ unsigned pkbf(float a, float b) {
#if __has_builtin(__builtin_amdgcn_cvt_pk_bf16_f32)
  auto r = __builtin_amdgcn_cvt_pk_bf16_f32(a, b);
  return __builtin_bit_cast(unsigned, r);
#else
  return f2bf_pack(a, b);
#endif
}

__device__ __forceinline__ void gl_lds16(const void* g, void* l) {
  __builtin_amdgcn_global_load_lds(
      (const __attribute__((address_space(1))) unsigned*)g,
      (__attribute__((address_space(3))) unsigned*)l, 16, 0, 0);
}

// Fragment-major layouts, per 32-s block = 8 slots * 1 KB = 8 KB (4096 ushort):
//  Kf slot kt, lane l=(h*32+s): K[s][d=kt*16+h*8+j]
//  Vf slot (dblk*2+t2), lane l=(h*32+dloc): V^T[d=dblk*32+dloc][s_perm]
//    s_perm = t2*16 + 4*h + (j&3) + 8*(j>>2) == S-MFMA C-reg order, so the
//    P B-fragment is exactly the packed acc registers (lane-local identity).

// ---------------- pre-pass (identical to R7, verified) ----------------
extern "C" __global__ __launch_bounds__(256)
void prep_kern(const float* __restrict__ Q, const float* __restrict__ K,
               const float* __restrict__ V,
               unsigned short* __restrict__ Qn, unsigned short* __restrict__ Kf,
               unsigned short* __restrict__ Vf) {
  __shared__ float Tf[32 * 130];
  __shared__ float Ps[32 * 8];
  __shared__ float Nr[32];
  __shared__ unsigned short Tb[32 * 128];
  const int t = threadIdx.x;
  const int bid = blockIdx.x;
  if (bid < 4096) {  // Q: one row per wave, row-major bf16 out
    const int lane = t & 63;
    const int r = bid * 4 + (t >> 6);
    float2 f = *(const float2*)(Q + (size_t)r * Dd + lane * 2);
    float ss = f.x * f.x + f.y * f.y;
#pragma unroll
    for (int m = 1; m < 64; m <<= 1) ss += __shfl_xor(ss, m, 64);
    float inv = 1.0f / fmaxf(sqrtf(ss), 1e-12f);
    *(unsigned*)(Qn + (size_t)r * Dd + lane * 2) = pkbf(f.x * inv, f.y * inv);
  } else if (bid < 4608) {  // K: 32-row block -> normalize -> frag-major
    const int kb = bid - 4096;
    const int b = kb & 7, sw = kb >> 3;
    const int sl = t >> 3, d0 = (t & 7) * 16;
    const float* src = K + ((size_t)(b * Ss + sw * 32 + sl)) * Dd + d0;
    float ss = 0.f;
#pragma unroll
    for (int i = 0; i < 4; ++i) {
      float4 v = *(const float4*)(src + i * 4);
      Tf[sl * 130 + d0 + i * 4 + 0] = v.x;
      Tf[sl * 130 + d0 + i * 4 + 1] = v.y;
      Tf[sl * 130 + d0 + i * 4 + 2] = v.z;
      Tf[sl * 130 + d0 + i * 4 + 3] = v.w;
      ss += v.x * v.x + v.y * v.y + v.z * v.z + v.w * v.w;
    }
    Ps[sl * 8 + (t & 7)] = ss;
    __syncthreads();
    if (t < 32) {
      float s = 0.f;
#pragma unroll
      for (int j = 0; j < 8; ++j) s += Ps[t * 8 + j];
      Nr[t] = 1.0f / fmaxf(sqrtf(s), 1e-12f);
    }
    __syncthreads();
    unsigned short* Ko = Kf + ((size_t)(b * 64 + sw)) * 4096;
#pragma unroll
    for (int p = 0; p < 2; ++p) {
      const int run = p * 256 + t;
      const int lane = run & 63, s = lane & 31, h = lane >> 5;
      const int d = (run >> 6) * 16 + h * 8;
      const float n = Nr[s];
      const float* row = &Tf[s * 130 + d];
      uint4 w;
      w.x = pkbf(row[0] * n, row[1] * n);
      w.y = pkbf(row[2] * n, row[3] * n);
      w.z = pkbf(row[4] * n, row[5] * n);
      w.w = pkbf(row[6] * n, row[7] * n);
      *(uint4*)(Ko + run * 8) = w;
    }
  } else {  // V: 32-row block -> transpose -> j-permuted frag-major
    const int vb = bid - 4608;
    const int b = vb & 7, sw = vb >> 3;
    const int sl = t >> 3, d0 = (t & 7) * 16;
    const float* src = V + ((size_t)(b * Ss + sw * 32 + sl)) * Dd + d0;
#pragma unroll
    for (int i = 0; i < 4; ++i) {
      float4 v = *(const float4*)(src + i * 4);
      *(unsigned*)&Tb[sl * 128 + d0 + i * 4]     = pkbf(v.x, v.y);
      *(unsigned*)&Tb[sl * 128 + d0 + i * 4 + 2] = pkbf(v.z, v.w);
    }
    __syncthreads();
    unsigned short* Vo = Vf + ((size_t)(b * 64 + sw)) * 4096;
#pragma unroll
    for (int p = 0; p < 2; ++p) {
      const int run = p * 256 + t;
      const int vslot = run >> 6, lane = run & 63;
      const int dloc = lane & 31, h = lane >> 5;
      const int dblk = vslot >> 1, t2 = vslot & 1;
      const int d = dblk * 32 + dloc;
      unsigned short w[8];
#pragma unroll
      for (int j = 0; j < 8; ++j) {
        const int sloc = t2 * 16 + 4 * h + (j & 3) + 8 * (j >> 2);
        w[j] = Tb[sloc * 128 + d];
      }
      *(uint4*)(Vo + run * 8) = *(uint4*)w;
    }
  }
}

// ---------------- main fused attention: specialized waves, DISJOINT loops ---
// grid 1024: gid = qt*32 + b*4 + sb; WG = 4 waves / 64 q-rows.
// Waves 0,1 (A): S = K.Q^T -> exp -> P to LDS.   VGPR path ~90.
// Waves 2,3 (B): O += V^T.P^T.                    VGPR path ~100.
// Separate loop bodies keep qf/o liveness disjoint -> both paths <=128 VGPR
// -> 4 waves/SIMD (16 waves/CU; LDS 40 KB -> 4 WG/CU). A(t+1) || B(t).
// Barrier counts match across branches: 1 prologue + 16 gates.
extern "C" __global__ __launch_bounds__(256, 4)
void attn_kern(const unsigned short* __restrict__ Qn,
               const unsigned short* __restrict__ Kf,
               const unsigned short* __restrict__ Vf,
               unsigned short* __restrict__ Op,
               float* __restrict__ Lp) {
  __shared__ unsigned short Kl[2][8 * 512];   // 16 KB K dbuf
  __shared__ unsigned short Vl[2][8 * 512];   // 16 KB V dbuf
  __shared__ unsigned short Pl[2][2][1024];   // 8 KB P dbuf [parity][qgroup]
  const int tid = threadIdx.x, wv = tid >> 6, lane = tid & 63;
  const int lm = lane & 31, h = lane >> 5;
  const int gid = blockIdx.x;
  const int qt = gid >> 5, b = (gid >> 2) & 7, sb = gid & 3;
  const int g = wv & 1;                        // q-group within WG
  const int qrow = qt * 64 + g * 32 + lm;
  const unsigned short* Kc = Kf + ((size_t)(b * 64 + sb * 16)) * 4096;
  const unsigned short* Vc = Vf + ((size_t)(b * 64 + sb * 16)) * 4096;

  if (wv < 2) {
    // ---------------- A path: producer ----------------
    bf16x8 qf[8];
    {
      const unsigned short* Qrow = Qn + ((size_t)(b * Ll + qrow)) * Dd;
#pragma unroll
      for (int kt = 0; kt < 8; ++kt)
        qf[kt] = *(const bf16x8*)(Qrow + kt * 16 + h * 8);
    }
    float lrun = 0.f;
    auto stageK = [&](int t) {
      const unsigned short* kb = Kc + (size_t)t * 4096;
#pragma unroll
      for (int i = 0; i < 4; ++i) {
        const int sl = g * 4 + i;
        gl_lds16(kb + sl * 512 + lane * 8, &Kl[t & 1][sl * 512]);
      }
    };
    auto computeS = [&](int t) {
      const int buf = t & 1;
      f32x16 acc;
#pragma unroll
      for (int r = 0; r < 16; ++r) acc[r] = 0.f;
#pragma unroll
      for (int kt = 0; kt < 8; ++kt) {
        bf16x8 kf = *(const bf16x8*)&Kl[buf][kt * 512 + lane * 8];
        acc = __builtin_amdgcn_mfma_f32_32x32x16_bf16(kf, qf[kt], acc, 0, 0, 0);
      }
#pragma unroll
      for (int t2 = 0; t2 < 2; ++t2) {
        float p[8];
#pragma unroll
        for (int j = 0; j < 8; ++j)
          p[j] = __builtin_amdgcn_exp2f(
              __builtin_fmaf(acc[t2 * 8 + j], SCALE_LOG2E, -SCALE_LOG2E));
        lrun += ((p[0] + p[1]) + (p[2] + p[3])) + ((p[4] + p[5]) + (p[6] + p[7]));
        uint4 fr;
        fr.x = pkbf(p[0], p[1]);
        fr.y = pkbf(p[2], p[3]);
        fr.z = pkbf(p[4], p[5]);
        fr.w = pkbf(p[6], p[7]);
        *(uint4*)&Pl[buf][g][(t2 * 64 + lane) * 8] = fr;  // ds_write_b128
      }
    };
    stageK(0); stageK(1);
    asm volatile("s_waitcnt vmcnt(0)\n\ts_barrier" ::: "memory");
    computeS(0);
#pragma unroll 1
    for (int t = 0; t < 16; ++t) {
      // gate: P(t) visible to B; K(t+1) (period-old) landed. K(t+2) will
      // be issued after, staying in flight across the next gate.
      asm volatile("s_waitcnt vmcnt(0) lgkmcnt(0)\n\ts_barrier" ::: "memory");
      if (t + 2 < 16) stageK(t + 2);
      if (t + 1 < 16) computeS(t + 1);
    }
    const float lt = lrun + __shfl_xor(lrun, 32, 64);
    if (h == 0) Lp[sb * NROWS + b * Ll + qrow] = lt;
  } else {
    // ---------------- B path: consumer ----------------
    f32x16 o[4];
#pragma unroll
    for (int i = 0; i < 4; ++i)
#pragma unroll
      for (int r = 0; r < 16; ++r) o[i][r] = 0.f;
    auto stageV = [&](int t) {
      const unsigned short* vb = Vc + (size_t)t * 4096;
#pragma unroll
      for (int i = 0; i < 4; ++i) {
        const int sl = g * 4 + i;
        gl_lds16(vb + sl * 512 + lane * 8, &Vl[t & 1][sl * 512]);
      }
    };
    auto computeO = [&](int t) {
      const int buf = t & 1;
#pragma unroll
      for (int t2 = 0; t2 < 2; ++t2) {
        bf16x8 pf = *(const bf16x8*)&Pl[buf][g][(t2 * 64 + lane) * 8];
#pragma unroll
        for (int dblk = 0; dblk < 4; ++dblk) {
          bf16x8 vf = *(const bf16x8*)&Vl[buf][(dblk * 2 + t2) * 512 + lane * 8];
          o[dblk] = __builtin_amdgcn_mfma_f32_32x32x16_bf16(vf, pf, o[dblk], 0, 0, 0);
        }
      }
    };
    stageV(0);
    asm volatile("s_waitcnt vmcnt(0)\n\ts_barrier" ::: "memory");
#pragma unroll 1
    for (int t = 0; t < 16; ++t) {
      // gate: V(t) (issued early last period) landed; P(t) visible.
      asm volatile("s_waitcnt vmcnt(0) lgkmcnt(0)\n\ts_barrier" ::: "memory");
      if (t + 1 < 16) stageV(t + 1);
      computeO(t);
    }
    unsigned short* Ob = Op + ((size_t)sb * NROWS + b * Ll + qrow) * Dd;
#pragma unroll
    for (int dblk = 0; dblk < 4; ++dblk)
#pragma unroll
      for (int gg = 0; gg < 4; ++gg) {
        uint2 w;
        w.x = pkbf(o[dblk][gg * 4 + 0], o[dblk][gg * 4 + 1]);
        w.y = pkbf(o[dblk][gg * 4 + 2], o[dblk][gg * 4 + 3]);
        *(uint2*)(Ob + dblk * 32 + gg * 8 + h * 4) = w;  // d = 32*dblk+8*gg+4*h
      }
  }
}

// ---------------- combine the NSB S-chunk partials (pure sum: shared max) ---
extern "C" __global__ __launch_bounds__(256)
void comb_kern(const unsigned short* __restrict__ Op,
               const float* __restrict__ Lp, float* __restrict__ Out) {
  const int idx = blockIdx.x * 256 + threadIdx.x;  // one thread per 4 d
  const int row = idx >> 5;
  const int dof = (idx & 31) * 4;
  float den = 0.f;
#pragma unroll
  for (int s = 0; s < NSB; ++s) den += Lp[s * NROWS + row];
  float a0 = 0.f, a1 = 0.f, a2 = 0.f, a3 = 0.f;
#pragma unroll
  for (int s = 0; s < NSB; ++s) {
    uint2 v = *(const uint2*)(Op + ((size_t)s * NROWS + row) * Dd + dof);
    a0 += __uint_as_float(v.x << 16);
    a1 += __uint_as_float(v.x & 0xffff0000u);
    a2 += __uint_as_float(v.y << 16);
    a3 += __uint_as_float(v.y & 0xffff0000u);
  }
  const float inv = 1.f / den;
  float4 r; r.x = a0 * inv; r.y = a1 * inv; r.z = a2 * inv; r.w = a3 * inv;
  *(float4*)(Out + (size_t)row * Dd + dof) = r;
}

extern "C" void kernel_launch(void* const* d_in, const int* in_sizes, int n_in,
                              void* d_out, int out_size, void* d_ws, size_t ws_size,
                              hipStream_t stream) {
  const float* Q = (const float*)d_in[0];
  const float* K = (const float*)d_in[1];
  const float* V = (const float*)d_in[2];
  float* Out = (float*)d_out;
  unsigned short* Qn = (unsigned short*)d_ws;                  // 4 MiB
  unsigned short* Kf = Qn + (size_t)NROWS * Dd;                // 4 MiB (frag-major)
  unsigned short* Vf = Kf + (size_t)NROWS * Dd;                // 4 MiB (frag-major, j-permuted)
  unsigned short* Op = Vf + (size_t)Bb * Dd * Ss;              // 16 MiB (bf16 partials)
  float* Lp = (float*)(Op + (size_t)NSB * NROWS * Dd);         // 256 KiB
  hipLaunchKernelGGL(prep_kern, dim3(4096 + 512 + 512), dim3(256), 0, stream,
                     Q, K, V, Qn, Kf, Vf);
  hipLaunchKernelGGL(attn_kern, dim3(1024), dim3(256), 0, stream, Qn, Kf, Vf, Op, Lp);
  hipLaunchKernelGGL(comb_kern, dim3(2048), dim3(256), 0, stream, Op, Lp, Out);
}